// Round 3
// baseline (566.562 us; speedup 1.0000x reference)
//
#include <hip/hip_runtime.h>
#include <hip/hip_bf16.h>
#include <hip/hip_fp16.h>
#include <math.h>

// Problem constants (fixed-shape problem)
#define N_NODES 50000
#define FIN     32
#define HID     64
#define HC      128     // HEADS*HID
#define NE      800000
#define NET     850000  // NE + N self loops
#define NI      10000   // interface nodes
#define NG      50      // graphs

__device__ __forceinline__ float lrelu(float x) { return x > 0.f ? x : 0.2f * x; }

// order-preserving float->uint encoding for atomicMax; 0 == "less than any float"
__device__ __forceinline__ unsigned fenc(float f) {
  unsigned u = __float_as_uint(f);
  return (u & 0x80000000u) ? ~u : (u | 0x80000000u);
}
__device__ __forceinline__ float fdec(unsigned u) {
  return (u & 0x80000000u) ? __uint_as_float(u ^ 0x80000000u) : __uint_as_float(~u);
}

__device__ __forceinline__ float rlf(float v, int l) {
  return __int_as_float(__builtin_amdgcn_readlane(__float_as_int(v), l));
}
__device__ __forceinline__ int rli(int v, int l) {
  return __builtin_amdgcn_readlane(v, l);
}

// ---------------- CSR build (unordered buckets) ----------------
__global__ void k_hist(const int* __restrict__ ei, int* __restrict__ deg) {
  int e = blockIdx.x * blockDim.x + threadIdx.x;
  if (e >= NET) return;
  int d = (e < NE) ? ei[NE + e] : (e - NE);
  atomicAdd(&deg[d], 1);
}

// block-scan + one global atomic per block for the base; bucket ranges are
// disjoint but NOT sorted by node id — aggregate only needs [start, start+deg).
__global__ void k_base(const int* __restrict__ deg, int* __restrict__ start,
                       int* __restrict__ gcur) {
  __shared__ int buf[256];
  __shared__ int basesh;
  int t = threadIdx.x;
  int i = blockIdx.x * 256 + t;
  int v = (i < N_NODES) ? deg[i] : 0;
  buf[t] = v; __syncthreads();
  for (int off = 1; off < 256; off <<= 1) {
    int a = (t >= off) ? buf[t - off] : 0;
    __syncthreads();
    buf[t] += a;
    __syncthreads();
  }
  if (t == 255) basesh = atomicAdd(gcur, buf[255]);
  __syncthreads();
  if (i < N_NODES) start[i] = basesh + buf[t] - v;
}

// edge record: {src(int bits), 1/ea.x, 1/ea.y, 0} — one 16B store / load
__global__ void k_scatter(const int* __restrict__ ei, const float* __restrict__ eattr,
                          const int* __restrict__ start, int* __restrict__ cursor,
                          float4* __restrict__ erec) {
  int e = blockIdx.x * blockDim.x + threadIdx.x;
  if (e >= NET) return;
  int s, d; float ex, ey;
  if (e < NE) {
    s = ei[e]; d = ei[NE + e];
    float2 ea = ((const float2*)eattr)[e];
    ex = 1.0f / ea.x; ey = 1.0f / ea.y;
  } else {
    s = d = e - NE; ex = 0.f; ey = 0.f;
  }
  int pos = start[d] + atomicAdd(&cursor[d], 1);
  erec[pos] = make_float4(__int_as_float(s), ex, ey, 0.f);
}

// ---------------- per-layer node linear + attention dots ----------------
// block = 128 threads (thread = output channel c = head*64+cc). W column kept in
// registers; h rows read as wave-uniform float4 broadcasts. xl written as packed
// __half2 (head-interleaved) via an LDS transpose: xl2h[n*64+cc] = (h0, h1).
template <int F>
__global__ void k_linear(const float* __restrict__ h, const float* __restrict__ W,
                         const float* __restrict__ attl, const float* __restrict__ attr,
                         __half2* __restrict__ xl2h, float* __restrict__ al,
                         float* __restrict__ ar) {
  __shared__ float lds[4][HC];
  const int c = threadIdx.x;
  const int head = c >> 6;
  const int cc = c & 63;
  float wcol[F];
#pragma unroll
  for (int k = 0; k < F; k++) wcol[k] = W[k * HC + c];
  const float attlv = attl[c];
  const float attrv = attr[c];
  for (int g = blockIdx.x; g < N_NODES / 4; g += gridDim.x) {
    const int n0 = g * 4;
    float acc[4] = {0.f, 0.f, 0.f, 0.f};
#pragma unroll
    for (int k4 = 0; k4 < F / 4; k4++) {
      float4 h4[4];
#pragma unroll
      for (int j = 0; j < 4; j++)
        h4[j] = *(const float4*)&h[(n0 + j) * F + k4 * 4];
#pragma unroll
      for (int j = 0; j < 4; j++) {
        acc[j] += h4[j].x * wcol[k4 * 4 + 0];
        acc[j] += h4[j].y * wcol[k4 * 4 + 1];
        acc[j] += h4[j].z * wcol[k4 * 4 + 2];
        acc[j] += h4[j].w * wcol[k4 * 4 + 3];
      }
    }
#pragma unroll
    for (int j = 0; j < 4; j++) {
      float lv = acc[j] * attlv, rv = acc[j] * attrv;
#pragma unroll
      for (int off = 32; off; off >>= 1) {
        lv += __shfl_xor(lv, off, 64);
        rv += __shfl_xor(rv, off, 64);
      }
      if (cc == 0) {
        al[(n0 + j) * 2 + head] = lv;
        ar[(n0 + j) * 2 + head] = rv;
      }
    }
    __syncthreads();  // previous iteration's packers done
#pragma unroll
    for (int j = 0; j < 4; j++) lds[j][c] = acc[j];
    __syncthreads();
#pragma unroll
    for (int r = 0; r < 2; r++) {
      int idx = c + r * 128;          // 0..255 -> (node j, channel cc)
      int j = idx >> 6, ccc = idx & 63;
      xl2h[(size_t)(n0 + j) * HID + ccc] =
          __floats2half2_rn(lds[j][ccc], lds[j][64 + ccc]);
    }
  }
}

// ---------------- per-layer edge aggregation ----------------
// 1 wave per dst node. Scores bounded (|e| <~ 2 — tanh-bounded inputs, glorot
// att vectors), so exp without max subtraction is numerically safe: single pass.
// Strip-parallel score compute, then serial readlane loop unrolled x4 so four
// independent 256B half2 gathers are in flight per wave (latency-bound stream).
// Edge-embedding term folded into per-head scalars (sum_p, sum_p*ea.{x,y}).
__global__ void k_aggregate(const __half2* __restrict__ xl2h, const float2* __restrict__ al2,
                            const float2* __restrict__ ar2, const int* __restrict__ start,
                            const int* __restrict__ degarr, const float4* __restrict__ erec,
                            const float* __restrict__ eW2, const float* __restrict__ eb1,
                            const float* __restrict__ bconv1, float* __restrict__ hout,
                            float* __restrict__ xmax, int first) {
  const int gid = blockIdx.x * 4 + (threadIdx.x >> 6);
  if (gid >= N_NODES) return;
  const int lane = threadIdx.x & 63;
  const int o0 = start[gid];
  const int deg = degarr[gid];
  const float2 arv = ar2[gid];

  float acc0 = 0.f, acc1 = 0.f;
  float ld0 = 0.f, ld1 = 0.f, lex0 = 0.f, ley0 = 0.f, lex1 = 0.f, ley1 = 0.f;
  for (int base = 0; base < deg; base += 64) {
    int j = base + lane;
    int s = 0; float p0 = 0.f, p1 = 0.f;
    if (j < deg) {
      float4 r = erec[o0 + j];
      s = __float_as_int(r.x);
      float2 alv = al2[s];
      p0 = __expf(lrelu(alv.x + arv.x));
      p1 = __expf(lrelu(alv.y + arv.y));
      ld0 += p0; ld1 += p1;
      lex0 += p0 * r.y; ley0 += p0 * r.z;
      lex1 += p1 * r.y; ley1 += p1 * r.z;
    }
    int slen = min(64, deg - base);
    int j2 = 0;
    for (; j2 + 4 <= slen; j2 += 4) {
      int sA = rli(s, j2), sB = rli(s, j2 + 1), sC = rli(s, j2 + 2), sD = rli(s, j2 + 3);
      float2 xA = __half22float2(xl2h[(size_t)sA * HID + lane]);
      float2 xB = __half22float2(xl2h[(size_t)sB * HID + lane]);
      float2 xC = __half22float2(xl2h[(size_t)sC * HID + lane]);
      float2 xD = __half22float2(xl2h[(size_t)sD * HID + lane]);
      acc0 += rlf(p0, j2)     * xA.x; acc1 += rlf(p1, j2)     * xA.y;
      acc0 += rlf(p0, j2 + 1) * xB.x; acc1 += rlf(p1, j2 + 1) * xB.y;
      acc0 += rlf(p0, j2 + 2) * xC.x; acc1 += rlf(p1, j2 + 2) * xC.y;
      acc0 += rlf(p0, j2 + 3) * xD.x; acc1 += rlf(p1, j2 + 3) * xD.y;
    }
    for (; j2 < slen; j2++) {
      int   sA  = rli(s, j2);
      float2 xA = __half22float2(xl2h[(size_t)sA * HID + lane]);
      acc0 += rlf(p0, j2) * xA.x; acc1 += rlf(p1, j2) * xA.y;
    }
  }
#pragma unroll
  for (int off = 32; off; off >>= 1) {
    ld0  += __shfl_xor(ld0, off, 64);
    ld1  += __shfl_xor(ld1, off, 64);
    lex0 += __shfl_xor(lex0, off, 64);
    ley0 += __shfl_xor(ley0, off, 64);
    lex1 += __shfl_xor(lex1, off, 64);
    ley1 += __shfl_xor(ley1, off, 64);
  }
  float t0 = acc0 + eW2[lane]      * lex0 + eW2[HC + lane]      * ley0 + eb1[lane]      * ld0;
  float t1 = acc1 + eW2[64 + lane] * lex1 + eW2[HC + 64 + lane] * ley1 + eb1[64 + lane] * ld1;
  float r = 0.5f * (t0 / (ld0 + 1e-16f) + t1 / (ld1 + 1e-16f)) + bconv1[lane];
  float hv = tanhf(r);
  hout[(size_t)gid * HID + lane] = hv;
  xmax[(size_t)gid * HID + lane] = first ? hv : fmaxf(xmax[(size_t)gid * HID + lane], hv);
}

// ---------------- pooling (atomic, high-TLP) ----------------
__global__ void k_pool1(const float* __restrict__ xmax, const int* __restrict__ ipos,
                        const int* __restrict__ batch, const float* __restrict__ gate_w,
                        const float* __restrict__ gate_b, float* __restrict__ add,
                        unsigned* __restrict__ mxE, float* __restrict__ cnt,
                        float* __restrict__ gate, unsigned* __restrict__ gmaxE) {
  int i = blockIdx.x * 4 + (threadIdx.x >> 6);
  if (i >= NI) return;
  int lane = threadIdx.x & 63;
  int node = ipos[i];
  int g = batch[node];
  float v = xmax[(size_t)node * HID + lane];
  atomicAdd(&add[g * HID + lane], v);
  atomicMax(&mxE[g * HID + lane], fenc(v));
  float gv = v * gate_w[lane];
#pragma unroll
  for (int off = 32; off; off >>= 1) gv += __shfl_xor(gv, off, 64);
  if (lane == 0) {
    float gs = gv + gate_b[0];
    gate[i] = gs;
    atomicMax(&gmaxE[g], fenc(gs));
    atomicAdd(&cnt[g], 1.f);
  }
}

__global__ void k_pool2(const float* __restrict__ xmax, const int* __restrict__ ipos,
                        const int* __restrict__ batch, const float* __restrict__ gate,
                        const unsigned* __restrict__ gmaxE, float* __restrict__ attp,
                        float* __restrict__ aden) {
  int i = blockIdx.x * 4 + (threadIdx.x >> 6);
  if (i >= NI) return;
  int lane = threadIdx.x & 63;
  int node = ipos[i];
  int g = batch[node];
  float a = __expf(gate[i] - fdec(gmaxE[g]));
  float v = xmax[(size_t)node * HID + lane];
  atomicAdd(&attp[g * HID + lane], a * v);
  if (lane == 0) atomicAdd(&aden[g], a);
}

__global__ void k_final(const float* __restrict__ add, const float* __restrict__ cnt,
                        const float* __restrict__ attp, const float* __restrict__ aden,
                        const unsigned* __restrict__ mxE, const float* __restrict__ lin1_w,
                        const float* __restrict__ lin1_b, const float* __restrict__ lin2_w,
                        const float* __restrict__ lin2_b, float* __restrict__ out) {
  __shared__ float pooled[4 * HID];
  __shared__ float zred[2 * HID];
  int g = blockIdx.x, t = threadIdx.x;  // 256 threads
  if (t < HID)            pooled[t] = add[g * HID + t];
  else if (t < 2 * HID)   pooled[t] = add[g * HID + (t - HID)] / fmaxf(cnt[g], 1.f);
  else if (t < 3 * HID)   pooled[t] = attp[g * HID + (t - 2 * HID)] / (aden[g] + 1e-16f);
  else                    pooled[t] = fdec(mxE[g * HID + (t - 3 * HID)]);
  __syncthreads();
  if (t < 2 * HID) {
    float z = lin1_b[t];
    for (int k = 0; k < 4 * HID; k++) z += pooled[k] * lin1_w[k * (2 * HID) + t];
    z = tanhf(z);
    zred[t] = z * lin2_w[t];
  }
  __syncthreads();
  if (t == 0) {
    float s = 0.f;
    for (int k = 0; k < 2 * HID; k++) s += zred[k];
    out[g] = s + lin2_b[0];
  }
}

extern "C" void kernel_launch(void* const* d_in, const int* in_sizes, int n_in,
                              void* d_out, int out_size, void* d_ws, size_t ws_size,
                              hipStream_t stream) {
  const float* x      = (const float*)d_in[0];
  const int*   ei     = (const int*)d_in[1];
  const float* eattr  = (const float*)d_in[2];
  const int*   batch  = (const int*)d_in[3];
  const int*   ipos   = (const int*)d_in[4];
  // d_in[5] = graph_num scalar (G=50, hardcoded)
  const float* W0     = (const float*)d_in[6];
  const float* attl0  = (const float*)d_in[7];
  const float* attr0  = (const float*)d_in[8];
  const float* W12    = (const float*)d_in[9];
  const float* attl12 = (const float*)d_in[10];
  const float* attr12 = (const float*)d_in[11];
  const float* eW     = (const float*)d_in[12];
  const float* eb     = (const float*)d_in[13];
  const float* bconv  = (const float*)d_in[14];
  const float* gate_w = (const float*)d_in[15];
  const float* gate_b = (const float*)d_in[16];
  const float* lin1_w = (const float*)d_in[17];
  const float* lin1_b = (const float*)d_in[18];
  const float* lin2_w = (const float*)d_in[19];
  const float* lin2_b = (const float*)d_in[20];
  float* out = (float*)d_out;

  char* ws = (char*)d_ws;
  size_t off = 0;
  auto alloc = [&](size_t elems) {
    void* p = ws + off;
    off += ((elems * 4 + 15) / 16) * 16;   // 16B-aligned slots
    return p;
  };
  // ---- zero-init region (contiguous, one memset) ----
  int*      deg    = (int*)alloc(N_NODES);
  int*      cursor = (int*)alloc(N_NODES);
  int*      gcur   = (int*)alloc(4);
  float*    addp   = (float*)alloc(NG * HID);
  float*    attp   = (float*)alloc(NG * HID);
  unsigned* mxE    = (unsigned*)alloc(NG * HID);
  float*    cnt    = (float*)alloc(64);
  unsigned* gmaxE  = (unsigned*)alloc(64);
  float*    aden   = (float*)alloc(64);
  size_t zbytes = off;
  // ---- rest ----
  int*     start = (int*)alloc(N_NODES);
  float*   erec  = (float*)alloc((size_t)NET * 4);
  __half2* xl2h  = (__half2*)alloc((size_t)N_NODES * HID);   // 4B each
  float*   al    = (float*)alloc((size_t)N_NODES * 2);
  float*   arr   = (float*)alloc((size_t)N_NODES * 2);
  float*   hbuf  = (float*)alloc((size_t)N_NODES * HID);
  float*   xmax  = (float*)alloc((size_t)N_NODES * HID);
  float*   gate  = (float*)alloc(NI);
  (void)ws_size; (void)in_sizes; (void)n_in; (void)out_size;

  hipMemsetAsync(d_ws, 0, zbytes, stream);
  k_hist<<<(NET + 255) / 256, 256, 0, stream>>>(ei, deg);
  k_base<<<(N_NODES + 255) / 256, 256, 0, stream>>>(deg, start, gcur);
  k_scatter<<<(NET + 255) / 256, 256, 0, stream>>>(ei, eattr, start, cursor, (float4*)erec);

  // layer 0
  k_linear<FIN><<<2500, 128, 0, stream>>>(x, W0, attl0, attr0, xl2h, al, arr);
  k_aggregate<<<N_NODES / 4, 256, 0, stream>>>(xl2h, (const float2*)al, (const float2*)arr,
                                               start, deg, (const float4*)erec,
                                               eW, eb, bconv, hbuf, xmax, 1);
  // layers 1,2
  for (int l = 0; l < 2; l++) {
    k_linear<HID><<<2500, 128, 0, stream>>>(hbuf, W12 + (size_t)l * HID * HC,
                                            attl12 + l * HC, attr12 + l * HC, xl2h, al, arr);
    k_aggregate<<<N_NODES / 4, 256, 0, stream>>>(xl2h, (const float2*)al, (const float2*)arr,
                                                 start, deg, (const float4*)erec,
                                                 eW + (l + 1) * 2 * HC, eb + (l + 1) * HC,
                                                 bconv + (l + 1) * HID, hbuf, xmax, 0);
  }

  k_pool1<<<NI / 4, 256, 0, stream>>>(xmax, ipos, batch, gate_w, gate_b, addp, mxE, cnt, gate, gmaxE);
  k_pool2<<<NI / 4, 256, 0, stream>>>(xmax, ipos, batch, gate, gmaxE, attp, aden);
  k_final<<<NG, 256, 0, stream>>>(addp, cnt, attp, aden, mxE, lin1_w, lin1_b, lin2_w, lin2_b, out);
}

// Round 4
// 440.367 us; speedup vs baseline: 1.2866x; 1.2866x over previous
//
#include <hip/hip_runtime.h>
#include <hip/hip_bf16.h>
#include <hip/hip_fp16.h>
#include <math.h>

// Problem constants (fixed-shape problem)
#define N_NODES 50000
#define FIN     32
#define HID     64
#define HC      128     // HEADS*HID
#define NE      800000
#define NET     850000  // NE + N self loops
#define NI      10000   // interface nodes
#define NG      50      // graphs
#define PB      8       // pooling blocks per graph

__device__ __forceinline__ float lrelu(float x) { return x > 0.f ? x : 0.2f * x; }

// order-preserving float->uint encoding for atomicMax; 0 == "less than any float"
__device__ __forceinline__ unsigned fenc(float f) {
  unsigned u = __float_as_uint(f);
  return (u & 0x80000000u) ? ~u : (u | 0x80000000u);
}
__device__ __forceinline__ float fdec(unsigned u) {
  return (u & 0x80000000u) ? __uint_as_float(u ^ 0x80000000u) : __uint_as_float(~u);
}

__device__ __forceinline__ float rlf(float v, int l) {
  return __int_as_float(__builtin_amdgcn_readlane(__float_as_int(v), l));
}
__device__ __forceinline__ int rli(int v, int l) {
  return __builtin_amdgcn_readlane(v, l);
}

// ---------------- CSR build (unordered buckets) ----------------
__global__ void k_hist(const int* __restrict__ ei, int* __restrict__ deg) {
  int e = blockIdx.x * blockDim.x + threadIdx.x;
  if (e >= NET) return;
  int d = (e < NE) ? ei[NE + e] : (e - NE);
  atomicAdd(&deg[d], 1);
}

// block-scan + one global atomic per block for the base; bucket ranges are
// disjoint but NOT sorted by node id — aggregate only needs [start, start+deg).
__global__ void k_base(const int* __restrict__ deg, int* __restrict__ start,
                       int* __restrict__ gcur) {
  __shared__ int buf[256];
  __shared__ int basesh;
  int t = threadIdx.x;
  int i = blockIdx.x * 256 + t;
  int v = (i < N_NODES) ? deg[i] : 0;
  buf[t] = v; __syncthreads();
  for (int off = 1; off < 256; off <<= 1) {
    int a = (t >= off) ? buf[t - off] : 0;
    __syncthreads();
    buf[t] += a;
    __syncthreads();
  }
  if (t == 255) basesh = atomicAdd(gcur, buf[255]);
  __syncthreads();
  if (i < N_NODES) start[i] = basesh + buf[t] - v;
}

// edge record: {src(int bits), 1/ea.x, 1/ea.y, 0} — one 16B store / load
__global__ void k_scatter(const int* __restrict__ ei, const float* __restrict__ eattr,
                          const int* __restrict__ start, int* __restrict__ cursor,
                          float4* __restrict__ erec) {
  int e = blockIdx.x * blockDim.x + threadIdx.x;
  if (e >= NET) return;
  int s, d; float ex, ey;
  if (e < NE) {
    s = ei[e]; d = ei[NE + e];
    float2 ea = ((const float2*)eattr)[e];
    ex = 1.0f / ea.x; ey = 1.0f / ea.y;
  } else {
    s = d = e - NE; ex = 0.f; ey = 0.f;
  }
  int pos = start[d] + atomicAdd(&cursor[d], 1);
  erec[pos] = make_float4(__int_as_float(s), ex, ey, 0.f);
}

// ---------------- per-layer node linear + attention dots ----------------
template <int F>
__global__ void k_linear(const float* __restrict__ h, const float* __restrict__ W,
                         const float* __restrict__ attl, const float* __restrict__ attr,
                         __half2* __restrict__ xl2h, float* __restrict__ al,
                         float* __restrict__ ar) {
  __shared__ float lds[4][HC];
  const int c = threadIdx.x;
  const int head = c >> 6;
  const int cc = c & 63;
  float wcol[F];
#pragma unroll
  for (int k = 0; k < F; k++) wcol[k] = W[k * HC + c];
  const float attlv = attl[c];
  const float attrv = attr[c];
  for (int g = blockIdx.x; g < N_NODES / 4; g += gridDim.x) {
    const int n0 = g * 4;
    float acc[4] = {0.f, 0.f, 0.f, 0.f};
#pragma unroll
    for (int k4 = 0; k4 < F / 4; k4++) {
      float4 h4[4];
#pragma unroll
      for (int j = 0; j < 4; j++)
        h4[j] = *(const float4*)&h[(n0 + j) * F + k4 * 4];
#pragma unroll
      for (int j = 0; j < 4; j++) {
        acc[j] += h4[j].x * wcol[k4 * 4 + 0];
        acc[j] += h4[j].y * wcol[k4 * 4 + 1];
        acc[j] += h4[j].z * wcol[k4 * 4 + 2];
        acc[j] += h4[j].w * wcol[k4 * 4 + 3];
      }
    }
#pragma unroll
    for (int j = 0; j < 4; j++) {
      float lv = acc[j] * attlv, rv = acc[j] * attrv;
#pragma unroll
      for (int off = 32; off; off >>= 1) {
        lv += __shfl_xor(lv, off, 64);
        rv += __shfl_xor(rv, off, 64);
      }
      if (cc == 0) {
        al[(n0 + j) * 2 + head] = lv;
        ar[(n0 + j) * 2 + head] = rv;
      }
    }
    __syncthreads();  // previous iteration's packers done
#pragma unroll
    for (int j = 0; j < 4; j++) lds[j][c] = acc[j];
    __syncthreads();
#pragma unroll
    for (int r = 0; r < 2; r++) {
      int idx = c + r * 128;          // 0..255 -> (node j, channel cc)
      int j = idx >> 6, ccc = idx & 63;
      xl2h[(size_t)(n0 + j) * HID + ccc] =
          __floats2half2_rn(lds[j][ccc], lds[j][64 + ccc]);
    }
  }
}

// ---------------- per-layer edge aggregation ----------------
__global__ void k_aggregate(const __half2* __restrict__ xl2h, const float2* __restrict__ al2,
                            const float2* __restrict__ ar2, const int* __restrict__ start,
                            const int* __restrict__ degarr, const float4* __restrict__ erec,
                            const float* __restrict__ eW2, const float* __restrict__ eb1,
                            const float* __restrict__ bconv1, float* __restrict__ hout,
                            float* __restrict__ xmax, int first) {
  const int gid = blockIdx.x * 4 + (threadIdx.x >> 6);
  if (gid >= N_NODES) return;
  const int lane = threadIdx.x & 63;
  const int o0 = start[gid];
  const int deg = degarr[gid];
  const float2 arv = ar2[gid];

  float acc0 = 0.f, acc1 = 0.f;
  float ld0 = 0.f, ld1 = 0.f, lex0 = 0.f, ley0 = 0.f, lex1 = 0.f, ley1 = 0.f;
  for (int base = 0; base < deg; base += 64) {
    int j = base + lane;
    int s = 0; float p0 = 0.f, p1 = 0.f;
    if (j < deg) {
      float4 r = erec[o0 + j];
      s = __float_as_int(r.x);
      float2 alv = al2[s];
      p0 = __expf(lrelu(alv.x + arv.x));
      p1 = __expf(lrelu(alv.y + arv.y));
      ld0 += p0; ld1 += p1;
      lex0 += p0 * r.y; ley0 += p0 * r.z;
      lex1 += p1 * r.y; ley1 += p1 * r.z;
    }
    int slen = min(64, deg - base);
    int j2 = 0;
    for (; j2 + 4 <= slen; j2 += 4) {
      int sA = rli(s, j2), sB = rli(s, j2 + 1), sC = rli(s, j2 + 2), sD = rli(s, j2 + 3);
      float2 xA = __half22float2(xl2h[(size_t)sA * HID + lane]);
      float2 xB = __half22float2(xl2h[(size_t)sB * HID + lane]);
      float2 xC = __half22float2(xl2h[(size_t)sC * HID + lane]);
      float2 xD = __half22float2(xl2h[(size_t)sD * HID + lane]);
      acc0 += rlf(p0, j2)     * xA.x; acc1 += rlf(p1, j2)     * xA.y;
      acc0 += rlf(p0, j2 + 1) * xB.x; acc1 += rlf(p1, j2 + 1) * xB.y;
      acc0 += rlf(p0, j2 + 2) * xC.x; acc1 += rlf(p1, j2 + 2) * xC.y;
      acc0 += rlf(p0, j2 + 3) * xD.x; acc1 += rlf(p1, j2 + 3) * xD.y;
    }
    for (; j2 < slen; j2++) {
      int   sA  = rli(s, j2);
      float2 xA = __half22float2(xl2h[(size_t)sA * HID + lane]);
      acc0 += rlf(p0, j2) * xA.x; acc1 += rlf(p1, j2) * xA.y;
    }
  }
#pragma unroll
  for (int off = 32; off; off >>= 1) {
    ld0  += __shfl_xor(ld0, off, 64);
    ld1  += __shfl_xor(ld1, off, 64);
    lex0 += __shfl_xor(lex0, off, 64);
    ley0 += __shfl_xor(ley0, off, 64);
    lex1 += __shfl_xor(lex1, off, 64);
    ley1 += __shfl_xor(ley1, off, 64);
  }
  float t0 = acc0 + eW2[lane]      * lex0 + eW2[HC + lane]      * ley0 + eb1[lane]      * ld0;
  float t1 = acc1 + eW2[64 + lane] * lex1 + eW2[HC + 64 + lane] * ley1 + eb1[64 + lane] * ld1;
  float r = 0.5f * (t0 / (ld0 + 1e-16f) + t1 / (ld1 + 1e-16f)) + bconv1[lane];
  float hv = tanhf(r);
  hout[(size_t)gid * HID + lane] = hv;
  xmax[(size_t)gid * HID + lane] = first ? hv : fmaxf(xmax[(size_t)gid * HID + lane], hv);
}

// ---------------- pooling ----------------
// bi = batch[ipos[i]] is monotone non-decreasing (batch monotone, ipos
// increasing), so each graph's interface nodes form one contiguous i-range.
// gstart[g]..gstart[g+1] bounds, computed generically for monotone bi.
__global__ void k_ranges(const int* __restrict__ ipos, const int* __restrict__ batch,
                         int* __restrict__ gstart) {
  int i = blockIdx.x * blockDim.x + threadIdx.x;
  if (i >= NI) return;
  int bi = batch[ipos[i]];
  int prev = (i > 0) ? batch[ipos[i - 1]] : -1;
  for (int g = prev + 1; g <= bi; g++) gstart[g] = i;
  if (i == NI - 1)
    for (int g = bi + 1; g <= NG; g++) gstart[g] = NI;
}

// Grid NG*PB blocks; block (g,m) reduces ~(range/PB) rows in registers, one
// atomic set per block (PB atomics/address instead of 200 per-node ones).
// Gate softmax uses exp(g) directly: |gate| <= sum|gate_w| ~ 19 << 88, safe,
// and exp(g)/sum(exp(g)) is analytically identical to the max-shifted form.
__global__ void k_pool(const float* __restrict__ xmax, const int* __restrict__ ipos,
                       const int* __restrict__ gstart, const float* __restrict__ gate_w,
                       const float* __restrict__ gate_b, float* __restrict__ add,
                       unsigned* __restrict__ mxE, float* __restrict__ cnt,
                       float* __restrict__ attp, float* __restrict__ aden) {
  __shared__ float red[4][3 * HID + 2];
  const int g = blockIdx.x / PB, m = blockIdx.x % PB;
  const int w = threadIdx.x >> 6, lane = threadIdx.x & 63;
  const int s0 = gstart[g], s1 = gstart[g + 1];
  const int len = s1 - s0;
  const int b0 = s0 + (len * m) / PB;
  const int b1 = s0 + (len * (m + 1)) / PB;
  const float gwv = gate_w[lane];
  const float gbv = gate_b[0];

  float padd = 0.f, pmax = -1e30f, pattp = 0.f, paden = 0.f, pcnt = 0.f;
  for (int i = b0 + w; i < b1; i += 4) {
    int node = ipos[i];
    float v = xmax[(size_t)node * HID + lane];
    padd += v;
    pmax = fmaxf(pmax, v);
    float gv = v * gwv;
#pragma unroll
    for (int off = 32; off; off >>= 1) gv += __shfl_xor(gv, off, 64);
    float e = __expf(gv + gbv);
    pattp += e * v;
    paden += e;   // wave-uniform; take lane 0's copy at reduce time
    pcnt += 1.f;
  }
  red[w][lane] = padd;
  red[w][HID + lane] = pmax;
  red[w][2 * HID + lane] = pattp;
  if (lane == 0) { red[w][3 * HID] = paden; red[w][3 * HID + 1] = pcnt; }
  __syncthreads();
  if (w == 0) {
    float addv  = red[0][lane] + red[1][lane] + red[2][lane] + red[3][lane];
    float maxv  = fmaxf(fmaxf(red[0][HID + lane], red[1][HID + lane]),
                        fmaxf(red[2][HID + lane], red[3][HID + lane]));
    float attpv = red[0][2 * HID + lane] + red[1][2 * HID + lane] +
                  red[2][2 * HID + lane] + red[3][2 * HID + lane];
    atomicAdd(&add[g * HID + lane], addv);
    atomicMax(&mxE[g * HID + lane], fenc(maxv));
    atomicAdd(&attp[g * HID + lane], attpv);
    if (lane == 0) {
      atomicAdd(&aden[g], red[0][3 * HID] + red[1][3 * HID] + red[2][3 * HID] + red[3][3 * HID]);
      atomicAdd(&cnt[g],  red[0][3 * HID + 1] + red[1][3 * HID + 1] +
                          red[2][3 * HID + 1] + red[3][3 * HID + 1]);
    }
  }
}

__global__ void k_final(const float* __restrict__ add, const float* __restrict__ cnt,
                        const float* __restrict__ attp, const float* __restrict__ aden,
                        const unsigned* __restrict__ mxE, const float* __restrict__ lin1_w,
                        const float* __restrict__ lin1_b, const float* __restrict__ lin2_w,
                        const float* __restrict__ lin2_b, float* __restrict__ out) {
  __shared__ float pooled[4 * HID];
  __shared__ float zred[2 * HID];
  int g = blockIdx.x, t = threadIdx.x;  // 256 threads
  if (t < HID)            pooled[t] = add[g * HID + t];
  else if (t < 2 * HID)   pooled[t] = add[g * HID + (t - HID)] / fmaxf(cnt[g], 1.f);
  else if (t < 3 * HID)   pooled[t] = attp[g * HID + (t - 2 * HID)] / (aden[g] + 1e-16f);
  else                    pooled[t] = fdec(mxE[g * HID + (t - 3 * HID)]);
  __syncthreads();
  if (t < 2 * HID) {
    float z = lin1_b[t];
    for (int k = 0; k < 4 * HID; k++) z += pooled[k] * lin1_w[k * (2 * HID) + t];
    z = tanhf(z);
    zred[t] = z * lin2_w[t];
  }
  __syncthreads();
  if (t == 0) {
    float s = 0.f;
    for (int k = 0; k < 2 * HID; k++) s += zred[k];
    out[g] = s + lin2_b[0];
  }
}

extern "C" void kernel_launch(void* const* d_in, const int* in_sizes, int n_in,
                              void* d_out, int out_size, void* d_ws, size_t ws_size,
                              hipStream_t stream) {
  const float* x      = (const float*)d_in[0];
  const int*   ei     = (const int*)d_in[1];
  const float* eattr  = (const float*)d_in[2];
  const int*   batch  = (const int*)d_in[3];
  const int*   ipos   = (const int*)d_in[4];
  // d_in[5] = graph_num scalar (G=50, hardcoded)
  const float* W0     = (const float*)d_in[6];
  const float* attl0  = (const float*)d_in[7];
  const float* attr0  = (const float*)d_in[8];
  const float* W12    = (const float*)d_in[9];
  const float* attl12 = (const float*)d_in[10];
  const float* attr12 = (const float*)d_in[11];
  const float* eW     = (const float*)d_in[12];
  const float* eb     = (const float*)d_in[13];
  const float* bconv  = (const float*)d_in[14];
  const float* gate_w = (const float*)d_in[15];
  const float* gate_b = (const float*)d_in[16];
  const float* lin1_w = (const float*)d_in[17];
  const float* lin1_b = (const float*)d_in[18];
  const float* lin2_w = (const float*)d_in[19];
  const float* lin2_b = (const float*)d_in[20];
  float* out = (float*)d_out;

  char* ws = (char*)d_ws;
  size_t off = 0;
  auto alloc = [&](size_t elems) {
    void* p = ws + off;
    off += ((elems * 4 + 15) / 16) * 16;   // 16B-aligned slots
    return p;
  };
  // ---- zero-init region (contiguous, one memset) ----
  int*      deg    = (int*)alloc(N_NODES);
  int*      cursor = (int*)alloc(N_NODES);
  int*      gcur   = (int*)alloc(4);
  float*    addp   = (float*)alloc(NG * HID);
  float*    attp   = (float*)alloc(NG * HID);
  unsigned* mxE    = (unsigned*)alloc(NG * HID);
  float*    cnt    = (float*)alloc(64);
  float*    aden   = (float*)alloc(64);
  size_t zbytes = off;
  // ---- rest ----
  int*     gstart = (int*)alloc(NG + 4);
  int*     start  = (int*)alloc(N_NODES);
  float*   erec   = (float*)alloc((size_t)NET * 4);
  __half2* xl2h   = (__half2*)alloc((size_t)N_NODES * HID);   // 4B each
  float*   al     = (float*)alloc((size_t)N_NODES * 2);
  float*   arr    = (float*)alloc((size_t)N_NODES * 2);
  float*   hbuf   = (float*)alloc((size_t)N_NODES * HID);
  float*   xmax   = (float*)alloc((size_t)N_NODES * HID);
  (void)ws_size; (void)in_sizes; (void)n_in; (void)out_size;

  hipMemsetAsync(d_ws, 0, zbytes, stream);
  k_hist<<<(NET + 255) / 256, 256, 0, stream>>>(ei, deg);
  k_base<<<(N_NODES + 255) / 256, 256, 0, stream>>>(deg, start, gcur);
  k_scatter<<<(NET + 255) / 256, 256, 0, stream>>>(ei, eattr, start, cursor, (float4*)erec);
  k_ranges<<<(NI + 255) / 256, 256, 0, stream>>>(ipos, batch, gstart);

  // layer 0
  k_linear<FIN><<<2500, 128, 0, stream>>>(x, W0, attl0, attr0, xl2h, al, arr);
  k_aggregate<<<N_NODES / 4, 256, 0, stream>>>(xl2h, (const float2*)al, (const float2*)arr,
                                               start, deg, (const float4*)erec,
                                               eW, eb, bconv, hbuf, xmax, 1);
  // layers 1,2
  for (int l = 0; l < 2; l++) {
    k_linear<HID><<<2500, 128, 0, stream>>>(hbuf, W12 + (size_t)l * HID * HC,
                                            attl12 + l * HC, attr12 + l * HC, xl2h, al, arr);
    k_aggregate<<<N_NODES / 4, 256, 0, stream>>>(xl2h, (const float2*)al, (const float2*)arr,
                                                 start, deg, (const float4*)erec,
                                                 eW + (l + 1) * 2 * HC, eb + (l + 1) * HC,
                                                 bconv + (l + 1) * HID, hbuf, xmax, 0);
  }

  k_pool<<<NG * PB, 256, 0, stream>>>(xmax, ipos, gstart, gate_w, gate_b,
                                      addp, mxE, cnt, attp, aden);
  k_final<<<NG, 256, 0, stream>>>(addp, cnt, attp, aden, mxE, lin1_w, lin1_b, lin2_w, lin2_b, out);
}

// Round 5
// 393.499 us; speedup vs baseline: 1.4398x; 1.1191x over previous
//
#include <hip/hip_runtime.h>
#include <hip/hip_bf16.h>
#include <hip/hip_fp16.h>
#include <math.h>

// Problem constants (fixed-shape problem)
#define N_NODES 50000
#define FIN     32
#define HID     64
#define HC      128     // HEADS*HID
#define NE      800000
#define NET     850000  // NE + N self loops
#define NI      10000   // interface nodes
#define NG      50      // graphs
#define PB      8       // pooling blocks per graph

__device__ __forceinline__ float lrelu(float x) { return x > 0.f ? x : 0.2f * x; }

// order-preserving float->uint encoding for atomicMax; 0 == "less than any float"
__device__ __forceinline__ unsigned fenc(float f) {
  unsigned u = __float_as_uint(f);
  return (u & 0x80000000u) ? ~u : (u | 0x80000000u);
}
__device__ __forceinline__ float fdec(unsigned u) {
  return (u & 0x80000000u) ? __uint_as_float(u ^ 0x80000000u) : __uint_as_float(~u);
}

__device__ __forceinline__ float rlf(float v, int l) {
  return __int_as_float(__builtin_amdgcn_readlane(__float_as_int(v), l));
}
__device__ __forceinline__ int rli(int v, int l) {
  return __builtin_amdgcn_readlane(v, l);
}

// ---------------- CSR build (unordered buckets, rank from histogram) ----------------
__global__ void k_histrank(const int* __restrict__ ei, int* __restrict__ deg,
                           int* __restrict__ rank) {
  int e = blockIdx.x * blockDim.x + threadIdx.x;
  if (e >= NET) return;
  int d = (e < NE) ? ei[NE + e] : (e - NE);
  rank[e] = atomicAdd(&deg[d], 1);
}

// block-scan + one global atomic per block for the base; bucket ranges are
// disjoint but NOT sorted by node id — aggregate only needs [start, start+deg).
__global__ void k_base(const int* __restrict__ deg, int* __restrict__ start,
                       int* __restrict__ gcur) {
  __shared__ int buf[256];
  __shared__ int basesh;
  int t = threadIdx.x;
  int i = blockIdx.x * 256 + t;
  int v = (i < N_NODES) ? deg[i] : 0;
  buf[t] = v; __syncthreads();
  for (int off = 1; off < 256; off <<= 1) {
    int a = (t >= off) ? buf[t - off] : 0;
    __syncthreads();
    buf[t] += a;
    __syncthreads();
  }
  if (t == 255) basesh = atomicAdd(gcur, buf[255]);
  __syncthreads();
  if (i < N_NODES) start[i] = basesh + buf[t] - v;
}

// edge record: 8B {src, half2(1/ea.x, 1/ea.y)} — pure streaming, no atomics
__global__ void k_scatter(const int* __restrict__ ei, const float* __restrict__ eattr,
                          const int* __restrict__ start, const int* __restrict__ rank,
                          int2* __restrict__ erec) {
  int e = blockIdx.x * blockDim.x + threadIdx.x;
  if (e >= NET) return;
  int s, d; float ex, ey;
  if (e < NE) {
    s = ei[e]; d = ei[NE + e];
    float2 ea = ((const float2*)eattr)[e];
    ex = 1.0f / ea.x; ey = 1.0f / ea.y;
  } else {
    s = d = e - NE; ex = 0.f; ey = 0.f;
  }
  int pos = start[d] + rank[e];
  __half2 ea2 = __floats2half2_rn(ex, ey);
  erec[pos] = make_int2(s, *(int*)&ea2);
}

// ---------------- per-layer node linear + attention dots ----------------
template <int F>
__global__ void k_linear(const float* __restrict__ h, const float* __restrict__ W,
                         const float* __restrict__ attl, const float* __restrict__ attr,
                         __half2* __restrict__ xl2h, float* __restrict__ al,
                         float* __restrict__ ar) {
  __shared__ float lds[4][HC];
  const int c = threadIdx.x;
  const int head = c >> 6;
  const int cc = c & 63;
  float wcol[F];
#pragma unroll
  for (int k = 0; k < F; k++) wcol[k] = W[k * HC + c];
  const float attlv = attl[c];
  const float attrv = attr[c];
  for (int g = blockIdx.x; g < N_NODES / 4; g += gridDim.x) {
    const int n0 = g * 4;
    float acc[4] = {0.f, 0.f, 0.f, 0.f};
#pragma unroll
    for (int k4 = 0; k4 < F / 4; k4++) {
      float4 h4[4];
#pragma unroll
      for (int j = 0; j < 4; j++)
        h4[j] = *(const float4*)&h[(n0 + j) * F + k4 * 4];
#pragma unroll
      for (int j = 0; j < 4; j++) {
        acc[j] += h4[j].x * wcol[k4 * 4 + 0];
        acc[j] += h4[j].y * wcol[k4 * 4 + 1];
        acc[j] += h4[j].z * wcol[k4 * 4 + 2];
        acc[j] += h4[j].w * wcol[k4 * 4 + 3];
      }
    }
#pragma unroll
    for (int j = 0; j < 4; j++) {
      float lv = acc[j] * attlv, rv = acc[j] * attrv;
#pragma unroll
      for (int off = 32; off; off >>= 1) {
        lv += __shfl_xor(lv, off, 64);
        rv += __shfl_xor(rv, off, 64);
      }
      if (cc == 0) {
        al[(n0 + j) * 2 + head] = lv;
        ar[(n0 + j) * 2 + head] = rv;
      }
    }
    __syncthreads();  // previous iteration's packers done
#pragma unroll
    for (int j = 0; j < 4; j++) lds[j][c] = acc[j];
    __syncthreads();
#pragma unroll
    for (int r = 0; r < 2; r++) {
      int idx = c + r * 128;          // 0..255 -> (node j, channel cc)
      int j = idx >> 6, ccc = idx & 63;
      xl2h[(size_t)(n0 + j) * HID + ccc] =
          __floats2half2_rn(lds[j][ccc], lds[j][64 + ccc]);
    }
  }
}

// ---------------- per-layer edge aggregation ----------------
// 1 wave per dst node; strip-parallel scores, serial readlane gather loop
// unrolled x8 with split accumulators (8 gathers in flight, short FMA chains).
__global__ void k_aggregate(const __half2* __restrict__ xl2h, const float2* __restrict__ al2,
                            const float2* __restrict__ ar2, const int* __restrict__ start,
                            const int* __restrict__ degarr, const int2* __restrict__ erec,
                            const float* __restrict__ eW2, const float* __restrict__ eb1,
                            const float* __restrict__ bconv1, float* __restrict__ hout) {
  const int gid = blockIdx.x * 4 + (threadIdx.x >> 6);
  if (gid >= N_NODES) return;
  const int lane = threadIdx.x & 63;
  const int o0 = start[gid];
  const int deg = degarr[gid];
  const float2 arv = ar2[gid];

  float accA0 = 0.f, accA1 = 0.f, accB0 = 0.f, accB1 = 0.f;
  float ld0 = 0.f, ld1 = 0.f, lex0 = 0.f, ley0 = 0.f, lex1 = 0.f, ley1 = 0.f;
  for (int base = 0; base < deg; base += 64) {
    int j = base + lane;
    int s = 0; float p0 = 0.f, p1 = 0.f;
    if (j < deg) {
      int2 r = erec[o0 + j];
      s = r.x;
      float2 eaf = __half22float2(*(__half2*)&r.y);
      float2 alv = al2[s];
      p0 = __expf(lrelu(alv.x + arv.x));
      p1 = __expf(lrelu(alv.y + arv.y));
      ld0 += p0; ld1 += p1;
      lex0 += p0 * eaf.x; ley0 += p0 * eaf.y;
      lex1 += p1 * eaf.x; ley1 += p1 * eaf.y;
    }
    int slen = min(64, deg - base);
    int j2 = 0;
    for (; j2 + 8 <= slen; j2 += 8) {
      float2 x0 = __half22float2(xl2h[(size_t)rli(s, j2)     * HID + lane]);
      float2 x1 = __half22float2(xl2h[(size_t)rli(s, j2 + 1) * HID + lane]);
      float2 x2 = __half22float2(xl2h[(size_t)rli(s, j2 + 2) * HID + lane]);
      float2 x3 = __half22float2(xl2h[(size_t)rli(s, j2 + 3) * HID + lane]);
      float2 x4 = __half22float2(xl2h[(size_t)rli(s, j2 + 4) * HID + lane]);
      float2 x5 = __half22float2(xl2h[(size_t)rli(s, j2 + 5) * HID + lane]);
      float2 x6 = __half22float2(xl2h[(size_t)rli(s, j2 + 6) * HID + lane]);
      float2 x7 = __half22float2(xl2h[(size_t)rli(s, j2 + 7) * HID + lane]);
      accA0 += rlf(p0, j2)     * x0.x; accA1 += rlf(p1, j2)     * x0.y;
      accB0 += rlf(p0, j2 + 1) * x1.x; accB1 += rlf(p1, j2 + 1) * x1.y;
      accA0 += rlf(p0, j2 + 2) * x2.x; accA1 += rlf(p1, j2 + 2) * x2.y;
      accB0 += rlf(p0, j2 + 3) * x3.x; accB1 += rlf(p1, j2 + 3) * x3.y;
      accA0 += rlf(p0, j2 + 4) * x4.x; accA1 += rlf(p1, j2 + 4) * x4.y;
      accB0 += rlf(p0, j2 + 5) * x5.x; accB1 += rlf(p1, j2 + 5) * x5.y;
      accA0 += rlf(p0, j2 + 6) * x6.x; accA1 += rlf(p1, j2 + 6) * x6.y;
      accB0 += rlf(p0, j2 + 7) * x7.x; accB1 += rlf(p1, j2 + 7) * x7.y;
    }
    for (; j2 + 4 <= slen; j2 += 4) {
      float2 x0 = __half22float2(xl2h[(size_t)rli(s, j2)     * HID + lane]);
      float2 x1 = __half22float2(xl2h[(size_t)rli(s, j2 + 1) * HID + lane]);
      float2 x2 = __half22float2(xl2h[(size_t)rli(s, j2 + 2) * HID + lane]);
      float2 x3 = __half22float2(xl2h[(size_t)rli(s, j2 + 3) * HID + lane]);
      accA0 += rlf(p0, j2)     * x0.x; accA1 += rlf(p1, j2)     * x0.y;
      accB0 += rlf(p0, j2 + 1) * x1.x; accB1 += rlf(p1, j2 + 1) * x1.y;
      accA0 += rlf(p0, j2 + 2) * x2.x; accA1 += rlf(p1, j2 + 2) * x2.y;
      accB0 += rlf(p0, j2 + 3) * x3.x; accB1 += rlf(p1, j2 + 3) * x3.y;
    }
    for (; j2 < slen; j2++) {
      float2 x0 = __half22float2(xl2h[(size_t)rli(s, j2) * HID + lane]);
      accA0 += rlf(p0, j2) * x0.x; accA1 += rlf(p1, j2) * x0.y;
    }
  }
  float acc0 = accA0 + accB0, acc1 = accA1 + accB1;
#pragma unroll
  for (int off = 32; off; off >>= 1) {
    ld0  += __shfl_xor(ld0, off, 64);
    ld1  += __shfl_xor(ld1, off, 64);
    lex0 += __shfl_xor(lex0, off, 64);
    ley0 += __shfl_xor(ley0, off, 64);
    lex1 += __shfl_xor(lex1, off, 64);
    ley1 += __shfl_xor(ley1, off, 64);
  }
  float t0 = acc0 + eW2[lane]      * lex0 + eW2[HC + lane]      * ley0 + eb1[lane]      * ld0;
  float t1 = acc1 + eW2[64 + lane] * lex1 + eW2[HC + 64 + lane] * ley1 + eb1[64 + lane] * ld1;
  float r = 0.5f * (t0 / (ld0 + 1e-16f) + t1 / (ld1 + 1e-16f)) + bconv1[lane];
  hout[(size_t)gid * HID + lane] = tanhf(r);
}

// ---------------- pooling ----------------
// bi = batch[ipos[i]] is monotone non-decreasing, so each graph's interface
// nodes form one contiguous i-range; gstart[g] bounds.
__global__ void k_ranges(const int* __restrict__ ipos, const int* __restrict__ batch,
                         int* __restrict__ gstart) {
  int i = blockIdx.x * blockDim.x + threadIdx.x;
  if (i >= NI) return;
  int bi = batch[ipos[i]];
  int prev = (i > 0) ? batch[ipos[i - 1]] : -1;
  for (int g = prev + 1; g <= bi; g++) gstart[g] = i;
  if (i == NI - 1)
    for (int g = bi + 1; g <= NG; g++) gstart[g] = NI;
}

// Grid NG*PB blocks; JK-max (over the 3 layer outputs) computed inline — only
// interface nodes ever need it. One atomic set per block.
__global__ void k_pool(const float* __restrict__ h0, const float* __restrict__ h1,
                       const float* __restrict__ h2, const int* __restrict__ ipos,
                       const int* __restrict__ gstart, const float* __restrict__ gate_w,
                       const float* __restrict__ gate_b, float* __restrict__ add,
                       unsigned* __restrict__ mxE, float* __restrict__ cnt,
                       float* __restrict__ attp, float* __restrict__ aden) {
  __shared__ float red[4][3 * HID + 2];
  const int g = blockIdx.x / PB, m = blockIdx.x % PB;
  const int w = threadIdx.x >> 6, lane = threadIdx.x & 63;
  const int s0 = gstart[g], s1 = gstart[g + 1];
  const int len = s1 - s0;
  const int b0 = s0 + (len * m) / PB;
  const int b1 = s0 + (len * (m + 1)) / PB;
  const float gwv = gate_w[lane];
  const float gbv = gate_b[0];

  float padd = 0.f, pmax = -1e30f, pattp = 0.f, paden = 0.f, pcnt = 0.f;
  for (int i = b0 + w; i < b1; i += 4) {
    size_t node = (size_t)ipos[i] * HID + lane;
    float v = fmaxf(fmaxf(h0[node], h1[node]), h2[node]);
    padd += v;
    pmax = fmaxf(pmax, v);
    float gv = v * gwv;
#pragma unroll
    for (int off = 32; off; off >>= 1) gv += __shfl_xor(gv, off, 64);
    float e = __expf(gv + gbv);   // |gate| << 88: exp-safe without max shift
    pattp += e * v;
    paden += e;   // wave-uniform
    pcnt += 1.f;
  }
  red[w][lane] = padd;
  red[w][HID + lane] = pmax;
  red[w][2 * HID + lane] = pattp;
  if (lane == 0) { red[w][3 * HID] = paden; red[w][3 * HID + 1] = pcnt; }
  __syncthreads();
  if (w == 0) {
    float addv  = red[0][lane] + red[1][lane] + red[2][lane] + red[3][lane];
    float maxv  = fmaxf(fmaxf(red[0][HID + lane], red[1][HID + lane]),
                        fmaxf(red[2][HID + lane], red[3][HID + lane]));
    float attpv = red[0][2 * HID + lane] + red[1][2 * HID + lane] +
                  red[2][2 * HID + lane] + red[3][2 * HID + lane];
    atomicAdd(&add[g * HID + lane], addv);
    atomicMax(&mxE[g * HID + lane], fenc(maxv));
    atomicAdd(&attp[g * HID + lane], attpv);
    if (lane == 0) {
      atomicAdd(&aden[g], red[0][3 * HID] + red[1][3 * HID] + red[2][3 * HID] + red[3][3 * HID]);
      atomicAdd(&cnt[g],  red[0][3 * HID + 1] + red[1][3 * HID + 1] +
                          red[2][3 * HID + 1] + red[3][3 * HID + 1]);
    }
  }
}

__global__ void k_final(const float* __restrict__ add, const float* __restrict__ cnt,
                        const float* __restrict__ attp, const float* __restrict__ aden,
                        const unsigned* __restrict__ mxE, const float* __restrict__ lin1_w,
                        const float* __restrict__ lin1_b, const float* __restrict__ lin2_w,
                        const float* __restrict__ lin2_b, float* __restrict__ out) {
  __shared__ float pooled[4 * HID];
  __shared__ float zred[2 * HID];
  int g = blockIdx.x, t = threadIdx.x;  // 256 threads
  if (t < HID)            pooled[t] = add[g * HID + t];
  else if (t < 2 * HID)   pooled[t] = add[g * HID + (t - HID)] / fmaxf(cnt[g], 1.f);
  else if (t < 3 * HID)   pooled[t] = attp[g * HID + (t - 2 * HID)] / (aden[g] + 1e-16f);
  else                    pooled[t] = fdec(mxE[g * HID + (t - 3 * HID)]);
  __syncthreads();
  if (t < 2 * HID) {
    float z = lin1_b[t];
    for (int k = 0; k < 4 * HID; k++) z += pooled[k] * lin1_w[k * (2 * HID) + t];
    z = tanhf(z);
    zred[t] = z * lin2_w[t];
  }
  __syncthreads();
  if (t == 0) {
    float s = 0.f;
    for (int k = 0; k < 2 * HID; k++) s += zred[k];
    out[g] = s + lin2_b[0];
  }
}

extern "C" void kernel_launch(void* const* d_in, const int* in_sizes, int n_in,
                              void* d_out, int out_size, void* d_ws, size_t ws_size,
                              hipStream_t stream) {
  const float* x      = (const float*)d_in[0];
  const int*   ei     = (const int*)d_in[1];
  const float* eattr  = (const float*)d_in[2];
  const int*   batch  = (const int*)d_in[3];
  const int*   ipos   = (const int*)d_in[4];
  // d_in[5] = graph_num scalar (G=50, hardcoded)
  const float* W0     = (const float*)d_in[6];
  const float* attl0  = (const float*)d_in[7];
  const float* attr0  = (const float*)d_in[8];
  const float* W12    = (const float*)d_in[9];
  const float* attl12 = (const float*)d_in[10];
  const float* attr12 = (const float*)d_in[11];
  const float* eW     = (const float*)d_in[12];
  const float* eb     = (const float*)d_in[13];
  const float* bconv  = (const float*)d_in[14];
  const float* gate_w = (const float*)d_in[15];
  const float* gate_b = (const float*)d_in[16];
  const float* lin1_w = (const float*)d_in[17];
  const float* lin1_b = (const float*)d_in[18];
  const float* lin2_w = (const float*)d_in[19];
  const float* lin2_b = (const float*)d_in[20];
  float* out = (float*)d_out;

  char* ws = (char*)d_ws;
  size_t off = 0;
  auto alloc = [&](size_t elems) {
    void* p = ws + off;
    off += ((elems * 4 + 15) / 16) * 16;   // 16B-aligned slots
    return p;
  };
  // ---- zero-init region (contiguous, one memset) ----
  int*      deg    = (int*)alloc(N_NODES);
  int*      gcur   = (int*)alloc(4);
  float*    addp   = (float*)alloc(NG * HID);
  float*    attp   = (float*)alloc(NG * HID);
  unsigned* mxE    = (unsigned*)alloc(NG * HID);
  float*    cnt    = (float*)alloc(64);
  float*    aden   = (float*)alloc(64);
  size_t zbytes = off;
  // ---- rest ----
  int*     gstart = (int*)alloc(NG + 4);
  int*     start  = (int*)alloc(N_NODES);
  int*     rank   = (int*)alloc(NET);
  int2*    erec   = (int2*)alloc((size_t)NET * 2);           // 8B records
  __half2* xl2h   = (__half2*)alloc((size_t)N_NODES * HID);  // 4B each
  float*   al     = (float*)alloc((size_t)N_NODES * 2);
  float*   arr    = (float*)alloc((size_t)N_NODES * 2);
  float*   h0     = (float*)alloc((size_t)N_NODES * HID);
  float*   h1     = (float*)alloc((size_t)N_NODES * HID);
  float*   h2     = (float*)alloc((size_t)N_NODES * HID);
  (void)ws_size; (void)in_sizes; (void)n_in; (void)out_size;

  hipMemsetAsync(d_ws, 0, zbytes, stream);
  k_histrank<<<(NET + 255) / 256, 256, 0, stream>>>(ei, deg, rank);
  k_base<<<(N_NODES + 255) / 256, 256, 0, stream>>>(deg, start, gcur);
  k_scatter<<<(NET + 255) / 256, 256, 0, stream>>>(ei, eattr, start, rank, erec);
  k_ranges<<<(NI + 255) / 256, 256, 0, stream>>>(ipos, batch, gstart);

  // layer 0
  k_linear<FIN><<<2500, 128, 0, stream>>>(x, W0, attl0, attr0, xl2h, al, arr);
  k_aggregate<<<N_NODES / 4, 256, 0, stream>>>(xl2h, (const float2*)al, (const float2*)arr,
                                               start, deg, erec, eW, eb, bconv, h0);
  // layer 1
  k_linear<HID><<<2500, 128, 0, stream>>>(h0, W12, attl12, attr12, xl2h, al, arr);
  k_aggregate<<<N_NODES / 4, 256, 0, stream>>>(xl2h, (const float2*)al, (const float2*)arr,
                                               start, deg, erec, eW + 2 * HC, eb + HC,
                                               bconv + HID, h1);
  // layer 2
  k_linear<HID><<<2500, 128, 0, stream>>>(h1, W12 + (size_t)HID * HC,
                                          attl12 + HC, attr12 + HC, xl2h, al, arr);
  k_aggregate<<<N_NODES / 4, 256, 0, stream>>>(xl2h, (const float2*)al, (const float2*)arr,
                                               start, deg, erec, eW + 4 * HC, eb + 2 * HC,
                                               bconv + 2 * HID, h2);

  k_pool<<<NG * PB, 256, 0, stream>>>(h0, h1, h2, ipos, gstart, gate_w, gate_b,
                                      addp, mxE, cnt, attp, aden);
  k_final<<<NG, 256, 0, stream>>>(addp, cnt, attp, aden, mxE, lin1_w, lin1_b, lin2_w, lin2_b, out);
}

// Round 6
// 341.590 us; speedup vs baseline: 1.6586x; 1.1520x over previous
//
#include <hip/hip_runtime.h>
#include <hip/hip_bf16.h>
#include <hip/hip_fp16.h>
#include <math.h>

// Problem constants (fixed-shape problem)
#define N_NODES 50000
#define FIN     32
#define HID     64
#define HC      128     // HEADS*HID
#define NE      800000
#define NET     850000  // NE + N self loops
#define NI      10000   // interface nodes
#define NG      50      // graphs
#define PB      8       // pooling blocks per graph

typedef _Float16 half8 __attribute__((ext_vector_type(8)));
typedef float float4v __attribute__((ext_vector_type(4)));

__device__ __forceinline__ float lrelu(float x) { return fmaxf(x, 0.2f * x); }

// order-preserving float->uint encoding for atomicMax; 0 == "less than any float"
__device__ __forceinline__ unsigned fenc(float f) {
  unsigned u = __float_as_uint(f);
  return (u & 0x80000000u) ? ~u : (u | 0x80000000u);
}
__device__ __forceinline__ float fdec(unsigned u) {
  return (u & 0x80000000u) ? __uint_as_float(u ^ 0x80000000u) : __uint_as_float(~u);
}

__device__ __forceinline__ float rlf(float v, int l) {
  return __int_as_float(__builtin_amdgcn_readlane(__float_as_int(v), l));
}
__device__ __forceinline__ int rli(int v, int l) {
  return __builtin_amdgcn_readlane(v, l);
}

// ---------------- CSR build (unordered buckets, rank from histogram) ----------------
__global__ void k_histrank(const int* __restrict__ ei, int* __restrict__ deg,
                           int* __restrict__ rank) {
  int e = blockIdx.x * blockDim.x + threadIdx.x;
  if (e >= NET) return;
  int d = (e < NE) ? ei[NE + e] : (e - NE);
  rank[e] = atomicAdd(&deg[d], 1);
}

__global__ void k_base(const int* __restrict__ deg, int* __restrict__ start,
                       int* __restrict__ gcur) {
  __shared__ int buf[256];
  __shared__ int basesh;
  int t = threadIdx.x;
  int i = blockIdx.x * 256 + t;
  int v = (i < N_NODES) ? deg[i] : 0;
  buf[t] = v; __syncthreads();
  for (int off = 1; off < 256; off <<= 1) {
    int a = (t >= off) ? buf[t - off] : 0;
    __syncthreads();
    buf[t] += a;
    __syncthreads();
  }
  if (t == 255) basesh = atomicAdd(gcur, buf[255]);
  __syncthreads();
  if (i < N_NODES) start[i] = basesh + buf[t] - v;
}

// edge record: 8B {src*256 (byte offset into xl2h), half2(1/ea.x, 1/ea.y)}
__global__ void k_scatter(const int* __restrict__ ei, const float* __restrict__ eattr,
                          const int* __restrict__ start, const int* __restrict__ rank,
                          int2* __restrict__ erec) {
  int e = blockIdx.x * blockDim.x + threadIdx.x;
  if (e >= NET) return;
  int s, d; float ex, ey;
  if (e < NE) {
    s = ei[e]; d = ei[NE + e];
    float2 ea = ((const float2*)eattr)[e];
    ex = 1.0f / ea.x; ey = 1.0f / ea.y;
  } else {
    s = d = e - NE; ex = 0.f; ey = 0.f;
  }
  int pos = start[d] + rank[e];
  __half2 ea2 = __floats2half2_rn(ex, ey);
  erec[pos] = make_int2(s << 8, *(int*)&ea2);
}

// ---------------- per-layer node linear via MFMA ----------------
// xl = h @ W  ([N x F] x [F x 128]) with fp16 inputs / fp32 accumulate.
// Block = 256 thr (4 waves), M-tile = 16 nodes (3125 blocks exactly).
// Wave w covers output cols [w*32, w*32+32) = two 16-wide N tiles; cols of one
// head per wave (w<2 -> head0). Epilogue: al/ar column-dots reduced in-register
// (shfl over the 16 cols) + LDS head-pairing to emit head-interleaved __half2.
// MFMA layouts (guide §3, m89/m91-verified): A[m=lane&15][k=(lane>>4)*8+j],
// B[k=(lane>>4)*8+j][n=lane&15], C/D[row=(lane>>4)*4+reg][col=lane&15].
template <int F>
__global__ __launch_bounds__(256) void k_linear_mfma(
    const float* __restrict__ h, const float* __restrict__ W,
    const float* __restrict__ attl, const float* __restrict__ attr,
    __half2* __restrict__ xl2h, float* __restrict__ al, float* __restrict__ ar) {
  __shared__ _Float16 hA[16 * F];
  __shared__ _Float16 hC[16 * 128];
  __shared__ float redl[16 * 4], redr[16 * 4];
  const int w = threadIdx.x >> 6, lane = threadIdx.x & 63;
  const int m = lane & 15, q = lane >> 4;
  const int n0 = blockIdx.x * 16;

  // stage A tile (16 consecutive node rows) as fp16
  for (int i = threadIdx.x; i < 16 * F; i += 256)
    hA[i] = (_Float16)h[(size_t)n0 * F + i];
  __syncthreads();

  half8 a0, a1;
#pragma unroll
  for (int j = 0; j < 8; j++) a0[j] = hA[m * F + q * 8 + j];
  if constexpr (F == 64) {
#pragma unroll
    for (int j = 0; j < 8; j++) a1[j] = hA[m * F + 32 + q * 8 + j];
  }

  const int c0 = w * 32;
  float4v acc[2];
  float pl[4] = {0.f, 0.f, 0.f, 0.f}, pr[4] = {0.f, 0.f, 0.f, 0.f};
#pragma unroll
  for (int t = 0; t < 2; t++) {
    const int colg = c0 + t * 16 + m;
    half8 b0;
#pragma unroll
    for (int j = 0; j < 8; j++) b0[j] = (_Float16)W[(q * 8 + j) * HC + colg];
    float4v z = {0.f, 0.f, 0.f, 0.f};
    acc[t] = __builtin_amdgcn_mfma_f32_16x16x32_f16(a0, b0, z, 0, 0, 0);
    if constexpr (F == 64) {
      half8 b1;
#pragma unroll
      for (int j = 0; j < 8; j++) b1[j] = (_Float16)W[(32 + q * 8 + j) * HC + colg];
      acc[t] = __builtin_amdgcn_mfma_f32_16x16x32_f16(a1, b1, acc[t], 0, 0, 0);
    }
    const float atl = attl[colg], atr = attr[colg];
#pragma unroll
    for (int reg = 0; reg < 4; reg++) {
      float val = acc[t][reg];
      hC[(q * 4 + reg) * 128 + colg] = (_Float16)val;
      pl[reg] += val * atl;
      pr[reg] += val * atr;
    }
  }
  // reduce attention dots over the 16 cols held within each quad
#pragma unroll
  for (int off = 1; off < 16; off <<= 1) {
#pragma unroll
    for (int reg = 0; reg < 4; reg++) {
      pl[reg] += __shfl_xor(pl[reg], off, 64);
      pr[reg] += __shfl_xor(pr[reg], off, 64);
    }
  }
  if (m == 0) {
#pragma unroll
    for (int reg = 0; reg < 4; reg++) {
      redl[(q * 4 + reg) * 4 + w] = pl[reg];
      redr[(q * 4 + reg) * 4 + w] = pr[reg];
    }
  }
  __syncthreads();
  if (threadIdx.x < 32) {
    int node = threadIdx.x >> 1, head = threadIdx.x & 1;
    al[(n0 + node) * 2 + head] = redl[node * 4 + head * 2] + redl[node * 4 + head * 2 + 1];
    ar[(n0 + node) * 2 + head] = redr[node * 4 + head * 2] + redr[node * 4 + head * 2 + 1];
  }
  for (int i = threadIdx.x; i < 16 * 64; i += 256) {
    int node = i >> 6, cc = i & 63;
    xl2h[(size_t)(n0 + node) * HID + cc] =
        __halves2half2(hC[node * 128 + cc], hC[node * 128 + 64 + cc]);
  }
}

// ---------------- per-layer edge aggregation ----------------
// 1 wave per dst node; strip-parallel scores, serial readlane gather loop
// unrolled x8. erec.x holds src*256 -> 32-bit base+offset addressing.
__global__ void k_aggregate(const __half2* __restrict__ xl2h, const float* __restrict__ alp,
                            const float2* __restrict__ ar2, const int* __restrict__ start,
                            const int* __restrict__ degarr, const int2* __restrict__ erec,
                            const float* __restrict__ eW2, const float* __restrict__ eb1,
                            const float* __restrict__ bconv1, float* __restrict__ hout) {
  const int gid = blockIdx.x * 4 + (threadIdx.x >> 6);
  if (gid >= N_NODES) return;
  const int lane = threadIdx.x & 63;
  const int lane4 = lane << 2;
  const int o0 = start[gid];
  const int deg = degarr[gid];
  const float2 arv = ar2[gid];
  const char* xbase = (const char*)xl2h;
  const char* albase = (const char*)alp;

  float accA0 = 0.f, accA1 = 0.f, accB0 = 0.f, accB1 = 0.f;
  float ld0 = 0.f, ld1 = 0.f, lex0 = 0.f, ley0 = 0.f, lex1 = 0.f, ley1 = 0.f;
  for (int base = 0; base < deg; base += 64) {
    int j = base + lane;
    int soff = 0; float p0 = 0.f, p1 = 0.f;
    if (j < deg) {
      int2 r = erec[o0 + j];
      soff = r.x;
      float2 eaf = __half22float2(*(__half2*)&r.y);
      float2 alv = *(const float2*)(albase + (soff >> 5));
      p0 = __expf(lrelu(alv.x + arv.x));
      p1 = __expf(lrelu(alv.y + arv.y));
      ld0 += p0; ld1 += p1;
      lex0 += p0 * eaf.x; ley0 += p0 * eaf.y;
      lex1 += p1 * eaf.x; ley1 += p1 * eaf.y;
    }
    int slen = min(64, deg - base);
    int j2 = 0;
    for (; j2 + 8 <= slen; j2 += 8) {
      float2 x0 = __half22float2(*(const __half2*)(xbase + rli(soff, j2)     + lane4));
      float2 x1 = __half22float2(*(const __half2*)(xbase + rli(soff, j2 + 1) + lane4));
      float2 x2 = __half22float2(*(const __half2*)(xbase + rli(soff, j2 + 2) + lane4));
      float2 x3 = __half22float2(*(const __half2*)(xbase + rli(soff, j2 + 3) + lane4));
      float2 x4 = __half22float2(*(const __half2*)(xbase + rli(soff, j2 + 4) + lane4));
      float2 x5 = __half22float2(*(const __half2*)(xbase + rli(soff, j2 + 5) + lane4));
      float2 x6 = __half22float2(*(const __half2*)(xbase + rli(soff, j2 + 6) + lane4));
      float2 x7 = __half22float2(*(const __half2*)(xbase + rli(soff, j2 + 7) + lane4));
      accA0 += rlf(p0, j2)     * x0.x; accA1 += rlf(p1, j2)     * x0.y;
      accB0 += rlf(p0, j2 + 1) * x1.x; accB1 += rlf(p1, j2 + 1) * x1.y;
      accA0 += rlf(p0, j2 + 2) * x2.x; accA1 += rlf(p1, j2 + 2) * x2.y;
      accB0 += rlf(p0, j2 + 3) * x3.x; accB1 += rlf(p1, j2 + 3) * x3.y;
      accA0 += rlf(p0, j2 + 4) * x4.x; accA1 += rlf(p1, j2 + 4) * x4.y;
      accB0 += rlf(p0, j2 + 5) * x5.x; accB1 += rlf(p1, j2 + 5) * x5.y;
      accA0 += rlf(p0, j2 + 6) * x6.x; accA1 += rlf(p1, j2 + 6) * x6.y;
      accB0 += rlf(p0, j2 + 7) * x7.x; accB1 += rlf(p1, j2 + 7) * x7.y;
    }
    for (; j2 + 4 <= slen; j2 += 4) {
      float2 x0 = __half22float2(*(const __half2*)(xbase + rli(soff, j2)     + lane4));
      float2 x1 = __half22float2(*(const __half2*)(xbase + rli(soff, j2 + 1) + lane4));
      float2 x2 = __half22float2(*(const __half2*)(xbase + rli(soff, j2 + 2) + lane4));
      float2 x3 = __half22float2(*(const __half2*)(xbase + rli(soff, j2 + 3) + lane4));
      accA0 += rlf(p0, j2)     * x0.x; accA1 += rlf(p1, j2)     * x0.y;
      accB0 += rlf(p0, j2 + 1) * x1.x; accB1 += rlf(p1, j2 + 1) * x1.y;
      accA0 += rlf(p0, j2 + 2) * x2.x; accA1 += rlf(p1, j2 + 2) * x2.y;
      accB0 += rlf(p0, j2 + 3) * x3.x; accB1 += rlf(p1, j2 + 3) * x3.y;
    }
    for (; j2 < slen; j2++) {
      float2 x0 = __half22float2(*(const __half2*)(xbase + rli(soff, j2) + lane4));
      accA0 += rlf(p0, j2) * x0.x; accA1 += rlf(p1, j2) * x0.y;
    }
  }
  float acc0 = accA0 + accB0, acc1 = accA1 + accB1;
#pragma unroll
  for (int off = 32; off; off >>= 1) {
    ld0  += __shfl_xor(ld0, off, 64);
    ld1  += __shfl_xor(ld1, off, 64);
    lex0 += __shfl_xor(lex0, off, 64);
    ley0 += __shfl_xor(ley0, off, 64);
    lex1 += __shfl_xor(lex1, off, 64);
    ley1 += __shfl_xor(ley1, off, 64);
  }
  float t0 = acc0 + eW2[lane]      * lex0 + eW2[HC + lane]      * ley0 + eb1[lane]      * ld0;
  float t1 = acc1 + eW2[64 + lane] * lex1 + eW2[HC + 64 + lane] * ley1 + eb1[64 + lane] * ld1;
  float r = 0.5f * (t0 / (ld0 + 1e-16f) + t1 / (ld1 + 1e-16f)) + bconv1[lane];
  hout[(size_t)gid * HID + lane] = tanhf(r);
}

// ---------------- pooling ----------------
__global__ void k_ranges(const int* __restrict__ ipos, const int* __restrict__ batch,
                         int* __restrict__ gstart) {
  int i = blockIdx.x * blockDim.x + threadIdx.x;
  if (i >= NI) return;
  int bi = batch[ipos[i]];
  int prev = (i > 0) ? batch[ipos[i - 1]] : -1;
  for (int g = prev + 1; g <= bi; g++) gstart[g] = i;
  if (i == NI - 1)
    for (int g = bi + 1; g <= NG; g++) gstart[g] = NI;
}

__global__ void k_pool(const float* __restrict__ h0, const float* __restrict__ h1,
                       const float* __restrict__ h2, const int* __restrict__ ipos,
                       const int* __restrict__ gstart, const float* __restrict__ gate_w,
                       const float* __restrict__ gate_b, float* __restrict__ add,
                       unsigned* __restrict__ mxE, float* __restrict__ cnt,
                       float* __restrict__ attp, float* __restrict__ aden) {
  __shared__ float red[4][3 * HID + 2];
  const int g = blockIdx.x / PB, m = blockIdx.x % PB;
  const int w = threadIdx.x >> 6, lane = threadIdx.x & 63;
  const int s0 = gstart[g], s1 = gstart[g + 1];
  const int len = s1 - s0;
  const int b0 = s0 + (len * m) / PB;
  const int b1 = s0 + (len * (m + 1)) / PB;
  const float gwv = gate_w[lane];
  const float gbv = gate_b[0];

  float padd = 0.f, pmax = -1e30f, pattp = 0.f, paden = 0.f, pcnt = 0.f;
  for (int i = b0 + w; i < b1; i += 4) {
    size_t node = (size_t)ipos[i] * HID + lane;
    float v = fmaxf(fmaxf(h0[node], h1[node]), h2[node]);
    padd += v;
    pmax = fmaxf(pmax, v);
    float gv = v * gwv;
#pragma unroll
    for (int off = 32; off; off >>= 1) gv += __shfl_xor(gv, off, 64);
    float e = __expf(gv + gbv);   // |gate| << 88: exp-safe without max shift
    pattp += e * v;
    paden += e;   // wave-uniform
    pcnt += 1.f;
  }
  red[w][lane] = padd;
  red[w][HID + lane] = pmax;
  red[w][2 * HID + lane] = pattp;
  if (lane == 0) { red[w][3 * HID] = paden; red[w][3 * HID + 1] = pcnt; }
  __syncthreads();
  if (w == 0) {
    float addv  = red[0][lane] + red[1][lane] + red[2][lane] + red[3][lane];
    float maxv  = fmaxf(fmaxf(red[0][HID + lane], red[1][HID + lane]),
                        fmaxf(red[2][HID + lane], red[3][HID + lane]));
    float attpv = red[0][2 * HID + lane] + red[1][2 * HID + lane] +
                  red[2][2 * HID + lane] + red[3][2 * HID + lane];
    atomicAdd(&add[g * HID + lane], addv);
    atomicMax(&mxE[g * HID + lane], fenc(maxv));
    atomicAdd(&attp[g * HID + lane], attpv);
    if (lane == 0) {
      atomicAdd(&aden[g], red[0][3 * HID] + red[1][3 * HID] + red[2][3 * HID] + red[3][3 * HID]);
      atomicAdd(&cnt[g],  red[0][3 * HID + 1] + red[1][3 * HID + 1] +
                          red[2][3 * HID + 1] + red[3][3 * HID + 1]);
    }
  }
}

__global__ void k_final(const float* __restrict__ add, const float* __restrict__ cnt,
                        const float* __restrict__ attp, const float* __restrict__ aden,
                        const unsigned* __restrict__ mxE, const float* __restrict__ lin1_w,
                        const float* __restrict__ lin1_b, const float* __restrict__ lin2_w,
                        const float* __restrict__ lin2_b, float* __restrict__ out) {
  __shared__ float pooled[4 * HID];
  __shared__ float zred[2 * HID];
  int g = blockIdx.x, t = threadIdx.x;  // 256 threads
  if (t < HID)            pooled[t] = add[g * HID + t];
  else if (t < 2 * HID)   pooled[t] = add[g * HID + (t - HID)] / fmaxf(cnt[g], 1.f);
  else if (t < 3 * HID)   pooled[t] = attp[g * HID + (t - 2 * HID)] / (aden[g] + 1e-16f);
  else                    pooled[t] = fdec(mxE[g * HID + (t - 3 * HID)]);
  __syncthreads();
  if (t < 2 * HID) {
    float z = lin1_b[t];
    for (int k = 0; k < 4 * HID; k++) z += pooled[k] * lin1_w[k * (2 * HID) + t];
    z = tanhf(z);
    zred[t] = z * lin2_w[t];
  }
  __syncthreads();
  if (t == 0) {
    float s = 0.f;
    for (int k = 0; k < 2 * HID; k++) s += zred[k];
    out[g] = s + lin2_b[0];
  }
}

extern "C" void kernel_launch(void* const* d_in, const int* in_sizes, int n_in,
                              void* d_out, int out_size, void* d_ws, size_t ws_size,
                              hipStream_t stream) {
  const float* x      = (const float*)d_in[0];
  const int*   ei     = (const int*)d_in[1];
  const float* eattr  = (const float*)d_in[2];
  const int*   batch  = (const int*)d_in[3];
  const int*   ipos   = (const int*)d_in[4];
  // d_in[5] = graph_num scalar (G=50, hardcoded)
  const float* W0     = (const float*)d_in[6];
  const float* attl0  = (const float*)d_in[7];
  const float* attr0  = (const float*)d_in[8];
  const float* W12    = (const float*)d_in[9];
  const float* attl12 = (const float*)d_in[10];
  const float* attr12 = (const float*)d_in[11];
  const float* eW     = (const float*)d_in[12];
  const float* eb     = (const float*)d_in[13];
  const float* bconv  = (const float*)d_in[14];
  const float* gate_w = (const float*)d_in[15];
  const float* gate_b = (const float*)d_in[16];
  const float* lin1_w = (const float*)d_in[17];
  const float* lin1_b = (const float*)d_in[18];
  const float* lin2_w = (const float*)d_in[19];
  const float* lin2_b = (const float*)d_in[20];
  float* out = (float*)d_out;

  char* ws = (char*)d_ws;
  size_t off = 0;
  auto alloc = [&](size_t elems) {
    void* p = ws + off;
    off += ((elems * 4 + 15) / 16) * 16;   // 16B-aligned slots
    return p;
  };
  // ---- zero-init region (contiguous, one memset) ----
  int*      deg    = (int*)alloc(N_NODES);
  int*      gcur   = (int*)alloc(4);
  float*    addp   = (float*)alloc(NG * HID);
  float*    attp   = (float*)alloc(NG * HID);
  unsigned* mxE    = (unsigned*)alloc(NG * HID);
  float*    cnt    = (float*)alloc(64);
  float*    aden   = (float*)alloc(64);
  size_t zbytes = off;
  // ---- rest ----
  int*     gstart = (int*)alloc(NG + 4);
  int*     start  = (int*)alloc(N_NODES);
  int*     rank   = (int*)alloc(NET);
  int2*    erec   = (int2*)alloc((size_t)NET * 2);           // 8B records
  __half2* xl2h   = (__half2*)alloc((size_t)N_NODES * HID);  // 4B each
  float*   al     = (float*)alloc((size_t)N_NODES * 2);
  float*   arr    = (float*)alloc((size_t)N_NODES * 2);
  float*   h0     = (float*)alloc((size_t)N_NODES * HID);
  float*   h1     = (float*)alloc((size_t)N_NODES * HID);
  float*   h2     = (float*)alloc((size_t)N_NODES * HID);
  (void)ws_size; (void)in_sizes; (void)n_in; (void)out_size;

  hipMemsetAsync(d_ws, 0, zbytes, stream);
  k_histrank<<<(NET + 255) / 256, 256, 0, stream>>>(ei, deg, rank);
  k_base<<<(N_NODES + 255) / 256, 256, 0, stream>>>(deg, start, gcur);
  k_scatter<<<(NET + 255) / 256, 256, 0, stream>>>(ei, eattr, start, rank, erec);
  k_ranges<<<(NI + 255) / 256, 256, 0, stream>>>(ipos, batch, gstart);

  // layer 0
  k_linear_mfma<FIN><<<N_NODES / 16, 256, 0, stream>>>(x, W0, attl0, attr0, xl2h, al, arr);
  k_aggregate<<<N_NODES / 4, 256, 0, stream>>>(xl2h, al, (const float2*)arr,
                                               start, deg, erec, eW, eb, bconv, h0);
  // layer 1
  k_linear_mfma<HID><<<N_NODES / 16, 256, 0, stream>>>(h0, W12, attl12, attr12, xl2h, al, arr);
  k_aggregate<<<N_NODES / 4, 256, 0, stream>>>(xl2h, al, (const float2*)arr,
                                               start, deg, erec, eW + 2 * HC, eb + HC,
                                               bconv + HID, h1);
  // layer 2
  k_linear_mfma<HID><<<N_NODES / 16, 256, 0, stream>>>(h1, W12 + (size_t)HID * HC,
                                                       attl12 + HC, attr12 + HC, xl2h, al, arr);
  k_aggregate<<<N_NODES / 4, 256, 0, stream>>>(xl2h, al, (const float2*)arr,
                                               start, deg, erec, eW + 4 * HC, eb + 2 * HC,
                                               bconv + 2 * HID, h2);

  k_pool<<<NG * PB, 256, 0, stream>>>(h0, h1, h2, ipos, gstart, gate_w, gate_b,
                                      addp, mxE, cnt, attp, aden);
  k_final<<<NG, 256, 0, stream>>>(addp, cnt, attp, aden, mxE, lin1_w, lin1_b, lin2_w, lin2_b, out);
}